// Round 2
// baseline (437.333 us; speedup 1.0000x reference)
//
#include <hip/hip_runtime.h>

// waspGridSpatialIntegral: out[:,0] = cumsum_x(in[:,0]), out[:,1] = cumsum_y(in[:,1])
// B=128, W=512, fp32. Memory-bound: 256 MiB in + 256 MiB out. Roofline ~85 us.

#define W 512
#define BATCH 128

// ---- channel 0: cumsum over x. One wave per 512-float row, 4 rows/block. ----
// Fully contiguous 1 KiB-per-instruction float4 loads at [lane] and [lane+64];
// two-segment wave scan stitches the halves.
__global__ __launch_bounds__(256) void cumsum_x_kernel(
    const float* __restrict__ in, float* __restrict__ out) {
    const int wave = threadIdx.x >> 6;
    const int lane = threadIdx.x & 63;
    const int row  = blockIdx.x * 4 + wave;   // [0, B*W)
    const int img  = row >> 9;
    const int y    = row & 511;
    const size_t base = (size_t)img * (2 * W * W) + (size_t)y * W;  // channel 0
    const float4* ip4 = (const float4*)(in + base);
    float4*       op4 = (float4*)(out + base);

    float4 A = ip4[lane];        // elements [4*lane, 4*lane+4)
    float4 C = ip4[lane + 64];   // elements [256+4*lane, 256+4*lane+4)

    // lane-local inclusive prefixes
    A.y += A.x; A.z += A.y; A.w += A.z;
    C.y += C.x; C.z += C.y; C.w += C.z;
    const float aT = A.w, cT = C.w;

    // wave inclusive scans of both segment totals
    float sA = aT, sC = cT;
    #pragma unroll
    for (int off = 1; off < 64; off <<= 1) {
        const float nA = __shfl_up(sA, off, 64);
        const float nC = __shfl_up(sC, off, 64);
        if (lane >= off) { sA += nA; sC += nC; }
    }
    const float T  = __shfl(sA, 63, 64);   // total of first 256 elements
    const float eA = sA - aT;              // exclusive offsets
    const float eC = sC - cT + T;

    A.x += eA; A.y += eA; A.z += eA; A.w += eA;
    C.x += eC; C.y += eC; C.z += eC; C.w += eC;
    op4[lane]      = A;
    op4[lane + 64] = C;
}

// ---- channel 1: cumsum over y. Block = (image, 64-col strip), 4 waves = ----
// 4 y-segments of 128 rows. Pass 1: segment sums (pure loads). LDS scan of
// segment totals. Pass 2: cumsum + store, software-pipelined; tile re-read
// hits L2 (64 cols x 512 rows x 4 B = 128 KB).
__global__ __launch_bounds__(256) void cumsum_y_kernel(
    const float* __restrict__ in, float* __restrict__ out) {
    const int img   = blockIdx.x >> 3;
    const int strip = blockIdx.x & 7;
    const int lx    = threadIdx.x & 63;
    const int seg   = threadIdx.x >> 6;          // 0..3
    const int x     = strip * 64 + lx;
    const size_t base = ((size_t)img * 2 + 1) * ((size_t)W * W) + (size_t)x
                        + (size_t)(seg * 128) * W;
    const float* ip = in  + base;
    float*       op = out + base;

    // pass 1: segment sum (loads only -> guaranteed deep batching)
    float s = 0.0f;
    for (int yy = 0; yy < 128; yy += 8) {
        float v[8];
        #pragma unroll
        for (int j = 0; j < 8; ++j) v[j] = ip[(size_t)(yy + j) * W];
        #pragma unroll
        for (int j = 0; j < 8; ++j) s += v[j];
    }

    __shared__ float segsum[4][64];
    segsum[seg][lx] = s;
    __syncthreads();
    float sum = 0.0f;
    if (seg > 0) sum += segsum[0][lx];
    if (seg > 1) sum += segsum[1][lx];
    if (seg > 2) sum += segsum[2][lx];

    // pass 2: cumsum + store, prefetch next batch before consuming current
    float v[8];
    #pragma unroll
    for (int j = 0; j < 8; ++j) v[j] = ip[(size_t)j * W];
    for (int yy = 0; yy < 128; yy += 8) {
        float w[8];
        const bool more = (yy + 8) < 128;
        if (more) {
            #pragma unroll
            for (int j = 0; j < 8; ++j) w[j] = ip[(size_t)(yy + 8 + j) * W];
        }
        #pragma unroll
        for (int j = 0; j < 8; ++j) { sum += v[j]; op[(size_t)(yy + j) * W] = sum; }
        if (more) {
            #pragma unroll
            for (int j = 0; j < 8; ++j) v[j] = w[j];
        }
    }
}

extern "C" void kernel_launch(void* const* d_in, const int* in_sizes, int n_in,
                              void* d_out, int out_size, void* d_ws, size_t ws_size,
                              hipStream_t stream) {
    const float* in = (const float*)d_in[0];
    float* out = (float*)d_out;
    cumsum_y_kernel<<<dim3(BATCH * 8), dim3(256), 0, stream>>>(in, out);      // 1024 blocks
    cumsum_x_kernel<<<dim3(BATCH * W / 4), dim3(256), 0, stream>>>(in, out);  // 16384 blocks
}